// Round 1
// baseline (16494.919 us; speedup 1.0000x reference)
//
#include <hip/hip_runtime.h>
#include <stdint.h>

typedef unsigned short u16;

// ---------- problem constants ----------
#define BB 128
#define TT 1024
#define DD 64
#define CHUNK 128
#define NCHUNK 8
#define MTOT (BB*TT)        // 131072
#define DT_C 0.01f

// ---------- ws layout (bytes) ----------
#define OFF_U1P   0u                 // u32[128*1024]  512KB  (U1 packed half2 along K)
#define OFF_W1P   524288u            // u32[32*1024]   128KB
#define OFF_W2P   655360u            // u32[128*64]    32KB
#define OFF_WD1P  688128u            // u32[128*64]    32KB
#define OFF_ACC   720896u            // f32[64]  [0]=lin [1]=rec [2]=x2
#define OFF_STC   721152u            // f32[128*256]   128KB (lstm1 c-state across chunks)
#define OFF_STH   852224u            // f32[128*256]   128KB (lstm1 h-state across chunks)
#define OFF_BIG   1048576u           // xz1c f16 chunk (32MB) -> xz2 f32 (32MB) -> jordan f32 (8MB)
#define OFF_EMB1  34603008u          // emb1 f16 (64MB) -> emb f32 (8MB)

typedef _Float16 h2_t __attribute__((ext_vector_type(2)));
union UH2 { uint32_t u; h2_t h; u16 s[2]; };

__device__ __forceinline__ float fdot2f(uint32_t a, uint32_t b, float c) {
#if __has_builtin(__builtin_amdgcn_fdot2)
  UH2 ua, ub; ua.u = a; ub.u = b;
  return __builtin_amdgcn_fdot2(ua.h, ub.h, c, false);
#else
  UH2 ua, ub; ua.u = a; ub.u = b;
  return c + (float)ua.h.x * (float)ub.h.x + (float)ua.h.y * (float)ub.h.y;
#endif
}

__device__ __forceinline__ uint32_t pk2(float a, float b) {
  UH2 u; u.h = h2_t{(_Float16)a, (_Float16)b}; return u.u;
}
__device__ __forceinline__ u16 f2us(float a) {
  UH2 u; u.h = h2_t{(_Float16)a, (_Float16)0.f}; return u.s[0];
}
__device__ __forceinline__ float us2f(u16 s) {
  UH2 u; u.u = (uint32_t)s; return (float)u.h.x;
}
__device__ __forceinline__ float rcp_(float x) {
#if __has_builtin(__builtin_amdgcn_rcpf)
  return __builtin_amdgcn_rcpf(x);
#else
  return 1.0f / x;
#endif
}
__device__ __forceinline__ float sigm(float x)  { return rcp_(1.0f + __expf(-x)); }
__device__ __forceinline__ float tanh_(float x) { return 1.0f - 2.0f * rcp_(__expf(2.0f*x) + 1.0f); }
__device__ __forceinline__ float lk(float v)    { return v > 0.f ? v : 0.3f*v; }

// ---------------- K0: weight prep (pack f16 pairs along K) + zero accumulators ----------------
__global__ __launch_bounds__(256) void k0_prep(
    const float* __restrict__ W1, const float* __restrict__ U1,
    const float* __restrict__ W2, const float* __restrict__ Wd1,
    uint32_t* __restrict__ U1P, uint32_t* __restrict__ W1P,
    uint32_t* __restrict__ W2P, uint32_t* __restrict__ Wd1P,
    float* __restrict__ acc)
{
  const int i0 = blockIdx.x*256 + threadIdx.x;
  const int st = gridDim.x*256;
  for (int i = i0; i < 131072; i += st) {
    int k2 = i >> 10, cc = i & 1023;
    U1P[i] = pk2(U1[(2*k2)*1024 + cc], U1[(2*k2+1)*1024 + cc]);
  }
  for (int i = i0; i < 32768; i += st) {
    int k2 = i >> 10, cc = i & 1023;
    W1P[i] = pk2(W1[(2*k2)*1024 + cc], W1[(2*k2+1)*1024 + cc]);
  }
  for (int i = i0; i < 8192; i += st) {
    int k2 = i >> 6, cc = i & 63;
    W2P[i]  = pk2(W2[(2*k2)*64 + cc],  W2[(2*k2+1)*64 + cc]);
    Wd1P[i] = pk2(Wd1[(2*k2)*64 + cc], Wd1[(2*k2+1)*64 + cc]);
  }
  if (i0 < 64) acc[i0] = 0.f;
}

// ---------------- K1: xz1 chunk = inputs[:, t0:t0+128, :] @ W1 + b1  (f16 out) ----------------
__global__ __launch_bounds__(256) void k1_xz(
    const float* __restrict__ x, const float* __restrict__ b1,
    const uint32_t* __restrict__ W1P, u16* __restrict__ xz1c, int t0)
{
  __shared__ uint32_t wlds[8192];     // [32 k2][256 c]
  __shared__ uint32_t alds[64*33];    // [64 r][32 k2] padded
  __shared__ float blds[256];
  const int tid = threadIdx.x;
  const int c0t = blockIdx.y * 256;
  const int r0 = blockIdx.x * 64;
  for (int i = tid; i < 8192; i += 256) {
    int k2 = i >> 8, cc = i & 255;
    wlds[i] = W1P[k2*1024 + c0t + cc];
  }
  blds[tid] = b1[c0t + tid];
  if (tid < 64) {
    int rc = r0 + tid;
    int bq = rc >> 7, tc = rc & 127;
    const float4* xr = (const float4*)(x + ((size_t)bq*TT + t0 + tc) * 64);
#pragma unroll
    for (int q = 0; q < 16; ++q) {
      float4 v = xr[q];
      alds[tid*33 + 2*q]   = pk2(v.x, v.y);
      alds[tid*33 + 2*q+1] = pk2(v.z, v.w);
    }
  }
  __syncthreads();
  const int r = tid & 63, grp = tid >> 6;
  float acc[64];
#pragma unroll
  for (int q = 0; q < 64; ++q) acc[q] = 0.f;
  const uint4* w4p = (const uint4*)wlds;
  for (int k2 = 0; k2 < 32; ++k2) {
    uint32_t a2 = alds[r*33 + k2];
#pragma unroll
    for (int jj = 0; jj < 16; ++jj) {
      uint4 w = w4p[k2*64 + grp*16 + jj];
      acc[4*jj+0] = fdot2f(a2, w.x, acc[4*jj+0]);
      acc[4*jj+1] = fdot2f(a2, w.y, acc[4*jj+1]);
      acc[4*jj+2] = fdot2f(a2, w.z, acc[4*jj+2]);
      acc[4*jj+3] = fdot2f(a2, w.w, acc[4*jj+3]);
    }
  }
  int rc = r0 + r;
  uint32_t* dst = (uint32_t*)(xz1c + (size_t)rc*1024 + c0t + grp*64);
  const float4* bl4 = (const float4*)blds;
#pragma unroll
  for (int jj = 0; jj < 16; ++jj) {
    float4 bv = bl4[grp*16 + jj];
    dst[2*jj]   = pk2(acc[4*jj+0] + bv.x, acc[4*jj+1] + bv.y);
    dst[2*jj+1] = pk2(acc[4*jj+2] + bv.z, acc[4*jj+3] + bv.w);
  }
}

// ---------------- LSTM1: per-batch recurrence over one 128-step chunk ----------------
__global__ __launch_bounds__(512) void lstm1_chunk(
    const u16* __restrict__ xz1c, const uint32_t* __restrict__ U1P,
    u16* __restrict__ emb1, float* __restrict__ stc, float* __restrict__ sth, int t0)
{
  __shared__ uint32_t ulds[32768];   // U1 rows k2=96..127, [1024 c][8 granules of 16B], XOR-swizzled  (128KB)
  __shared__ uint32_t hsh[128];      // h as packed half2 (256 halves)
  __shared__ float2 zsh[256];        // (sig(f), sig(o)) exchange

  const int j = threadIdx.x;
  const int b = blockIdx.x;
  const int c0 = j, c1 = j + 512;

  uint32_t ur0[96], ur1[96];
#pragma unroll
  for (int r = 0; r < 96; ++r) {
    ur0[r] = U1P[r*1024 + c0];
    ur1[r] = U1P[r*1024 + c1];
  }
  {
    const int m0 = c0 & 7;  // c1&7 == c0&7
#pragma unroll
    for (int g = 0; g < 8; ++g) {
      uint4 v0, v1;
      v0.x = U1P[(96+4*g+0)*1024 + c0]; v0.y = U1P[(96+4*g+1)*1024 + c0];
      v0.z = U1P[(96+4*g+2)*1024 + c0]; v0.w = U1P[(96+4*g+3)*1024 + c0];
      v1.x = U1P[(96+4*g+0)*1024 + c1]; v1.y = U1P[(96+4*g+1)*1024 + c1];
      v1.z = U1P[(96+4*g+2)*1024 + c1]; v1.w = U1P[(96+4*g+3)*1024 + c1];
      int gp = (g ^ m0) * 4;
      *(uint4*)&ulds[c0*32 + gp] = v0;
      *(uint4*)&ulds[c1*32 + gp] = v1;
    }
  }
  float cst = 0.f, hlast = 0.f;
  if (j < 256) {
    float hv = 0.f;
    if (t0 != 0) { cst = stc[b*256 + j]; hv = sth[b*256 + j]; }
    hlast = hv;
    ((u16*)hsh)[j] = f2us(hv);
  }
  __syncthreads();

  const u16* xzb = xz1c + (size_t)b * CHUNK * 1024;
  u16 xv0 = xzb[c0];
  u16 xv1 = xzb[c1];
  const int m0 = c0 & 7;

  for (int t = 0; t < CHUNK; ++t) {
    u16 nx0 = 0, nx1 = 0;
    if (t + 1 < CHUNK) {
      nx0 = xzb[(size_t)(t+1)*1024 + c0];
      nx1 = xzb[(size_t)(t+1)*1024 + c1];
    }
    float a0 = us2f(xv0), a1 = us2f(xv1);
    float p0 = 0.f, p1 = 0.f;
    const uint4* h4p = (const uint4*)hsh;
#pragma unroll
    for (int r = 0; r < 24; ++r) {
      uint4 h4 = h4p[r];
      a0 = fdot2f(ur0[4*r+0], h4.x, a0);
      p0 = fdot2f(ur0[4*r+1], h4.y, p0);
      a0 = fdot2f(ur0[4*r+2], h4.z, a0);
      p0 = fdot2f(ur0[4*r+3], h4.w, p0);
      a1 = fdot2f(ur1[4*r+0], h4.x, a1);
      p1 = fdot2f(ur1[4*r+1], h4.y, p1);
      a1 = fdot2f(ur1[4*r+2], h4.z, a1);
      p1 = fdot2f(ur1[4*r+3], h4.w, p1);
    }
#pragma unroll
    for (int g = 0; g < 8; ++g) {
      uint4 h4 = h4p[24 + g];
      int gp = (g ^ m0) * 4;
      uint4 u0 = *(const uint4*)&ulds[c0*32 + gp];
      uint4 u1 = *(const uint4*)&ulds[c1*32 + gp];
      a0 = fdot2f(u0.x, h4.x, a0);
      p0 = fdot2f(u0.y, h4.y, p0);
      a0 = fdot2f(u0.z, h4.z, a0);
      p0 = fdot2f(u0.w, h4.w, p0);
      a1 = fdot2f(u1.x, h4.x, a1);
      p1 = fdot2f(u1.y, h4.y, p1);
      a1 = fdot2f(u1.z, h4.z, a1);
      p1 = fdot2f(u1.w, h4.w, p1);
    }
    float z0 = a0 + p0, z1 = a1 + p1;
    float s0, s1;
    if (j >= 256) {
      s0 = sigm(z0); s1 = sigm(z1);          // f_j, o_j (cols j, j+512 for j>=256)
      zsh[j - 256] = make_float2(s0, s1);
    } else {
      s0 = sigm(z0);                          // i_j
      s1 = tanh_(z1);                         // g_j
    }
    __syncthreads();
    if (j < 256) {
      float2 fo = zsh[j];
      cst = fo.x * cst + s0 * s1;
      float hval = fo.y * tanh_(cst);
      hlast = hval;
      u16 hu = f2us(hval);
      ((u16*)hsh)[j] = hu;
      emb1[((size_t)b*TT + t0 + t)*256 + j] = hu;
    }
    __syncthreads();
    xv0 = nx0; xv1 = nx1;
  }
  if (j < 256) { stc[b*256 + j] = cst; sth[b*256 + j] = hlast; }
}

// ---------------- K2: xz2 = emb1 @ W2 + b2  (f32 out) ----------------
__global__ __launch_bounds__(256) void k2_xz2(
    const uint32_t* __restrict__ emb1u, const uint32_t* __restrict__ W2P,
    const float* __restrict__ b2, float* __restrict__ xz2)
{
  __shared__ uint32_t alds[64*129];   // [64 r][128 k2] padded
  const int tid = threadIdx.x;
  const int r0 = blockIdx.x * 64;
  for (int i = tid; i < 8192; i += 256) {
    int row = i >> 7, k2 = i & 127;
    alds[row*129 + k2] = emb1u[(size_t)(r0 + row)*128 + k2];
  }
  __syncthreads();
  const int r = tid & 63, grp = tid >> 6;
  float acc[16];
#pragma unroll
  for (int q = 0; q < 16; ++q) acc[q] = 0.f;
  for (int k2 = 0; k2 < 128; ++k2) {
    uint32_t a2 = alds[r*129 + k2];
    const uint4* wp = (const uint4*)(W2P + k2*64 + grp*16);
#pragma unroll
    for (int q = 0; q < 4; ++q) {
      uint4 w = wp[q];
      acc[4*q+0] = fdot2f(a2, w.x, acc[4*q+0]);
      acc[4*q+1] = fdot2f(a2, w.y, acc[4*q+1]);
      acc[4*q+2] = fdot2f(a2, w.z, acc[4*q+2]);
      acc[4*q+3] = fdot2f(a2, w.w, acc[4*q+3]);
    }
  }
  float* dst = xz2 + (size_t)(r0 + r)*64 + grp*16;
#pragma unroll
  for (int q = 0; q < 4; ++q) {
    float4 bv = *(const float4*)(b2 + grp*16 + 4*q);
    float4 o;
    o.x = acc[4*q+0]+bv.x; o.y = acc[4*q+1]+bv.y;
    o.z = acc[4*q+2]+bv.z; o.w = acc[4*q+3]+bv.w;
    *(float4*)(dst + 4*q) = o;
  }
}

// ---------------- LSTM2: per-batch, 16 hidden units ----------------
__global__ __launch_bounds__(64) void lstm2_k(
    const float* __restrict__ xz2, const float* __restrict__ U2,
    float* __restrict__ emb)
{
  __shared__ float hsh[16];
  __shared__ float zsh[64];
  const int j = threadIdx.x;
  const int b = blockIdx.x;
  float u2[16];
#pragma unroll
  for (int k = 0; k < 16; ++k) u2[k] = U2[k*64 + j];
  if (j < 16) hsh[j] = 0.f;
  float cst = 0.f;
  __syncthreads();
  const float* xb = xz2 + (size_t)b * TT * 64;
  float xv = xb[j];
  for (int t = 0; t < TT; ++t) {
    float nx = 0.f;
    if (t + 1 < TT) nx = xb[(size_t)(t+1)*64 + j];
    float z = xv;
#pragma unroll
    for (int k = 0; k < 16; ++k) z += hsh[k] * u2[k];
    float av = (j >= 32 && j < 48) ? tanh_(z) : sigm(z);
    zsh[j] = av;
    __syncthreads();
    if (j < 16) {
      float iv = zsh[j], fv = zsh[j+16], gv = zsh[j+32], ov = zsh[j+48];
      cst = fv * cst + iv * gv;
      float hval = ov * tanh_(cst);
      hsh[j] = hval;
      emb[((size_t)b*TT + t)*16 + j] = hval;
    }
    __syncthreads();
    xv = nx;
  }
}

// ---------------- K4a: oreal/ocplx MLPs -> jordan, lin-loss partial ----------------
__global__ __launch_bounds__(256) void k4a_jordan(
    const float* __restrict__ emb,
    const float* __restrict__ Ar0, const float* __restrict__ br0,
    const float* __restrict__ Ar1, const float* __restrict__ br1,
    const float* __restrict__ Ac0, const float* __restrict__ bc0,
    const float* __restrict__ Ac1, const float* __restrict__ bc1,
    float* __restrict__ jordan, float* __restrict__ acc)
{
  __shared__ float wr0[1024], wr1[1024], wc0[1024], wc1[1024];
  __shared__ float bs0[128], bs2[128];
  __shared__ float bs1[8], bs3[8];
  __shared__ float red[256];
  const int tid = threadIdx.x;
  for (int i = tid; i < 1024; i += 256) {
    wr0[i] = Ar0[i]; wr1[i] = Ar1[i]; wc0[i] = Ac0[i]; wc1[i] = Ac1[i];
  }
  if (tid < 128) { bs0[tid] = br0[tid]; bs2[tid] = bc0[tid]; }
  if (tid < 8)   { bs1[tid] = br1[tid]; bs3[tid] = bc1[tid]; }
  __syncthreads();
  const int e = blockIdx.x * 256 + tid;
  float em[16];
  {
    const float4* ep = (const float4*)(emb + (size_t)e*16);
#pragma unroll
    for (int q = 0; q < 4; ++q) {
      float4 v = ep[q];
      em[4*q+0]=v.x; em[4*q+1]=v.y; em[4*q+2]=v.z; em[4*q+3]=v.w;
    }
  }
  float ar[8], ac_[8];
#pragma unroll
  for (int o = 0; o < 8; ++o) { ar[o] = bs1[o]; ac_[o] = bs3[o]; }
  for (int hb = 0; hb < 128; hb += 4) {
    float4 hr = *(const float4*)(bs0 + hb);
    float4 hc = *(const float4*)(bs2 + hb);
#pragma unroll
    for (int k = 0; k < 8; ++k) {
      float4 w = *(const float4*)(wr0 + k*128 + hb);
      hr.x += em[k]*w.x; hr.y += em[k]*w.y; hr.z += em[k]*w.z; hr.w += em[k]*w.w;
      float4 v = *(const float4*)(wc0 + k*128 + hb);
      hc.x += em[8+k]*v.x; hc.y += em[8+k]*v.y; hc.z += em[8+k]*v.z; hc.w += em[8+k]*v.w;
    }
    hr.x = lk(hr.x); hr.y = lk(hr.y); hr.z = lk(hr.z); hr.w = lk(hr.w);
    hc.x = lk(hc.x); hc.y = lk(hc.y); hc.z = lk(hc.z); hc.w = lk(hc.w);
#pragma unroll
    for (int q = 0; q < 4; ++q) {
      float hv = (q==0) ? hr.x : (q==1) ? hr.y : (q==2) ? hr.z : hr.w;
      float gv = (q==0) ? hc.x : (q==1) ? hc.y : (q==2) ? hc.z : hc.w;
      float4 wA = *(const float4*)(wr1 + (hb+q)*8);
      float4 wB = *(const float4*)(wr1 + (hb+q)*8 + 4);
      ar[0]+=hv*wA.x; ar[1]+=hv*wA.y; ar[2]+=hv*wA.z; ar[3]+=hv*wA.w;
      ar[4]+=hv*wB.x; ar[5]+=hv*wB.y; ar[6]+=hv*wB.z; ar[7]+=hv*wB.w;
      float4 cA = *(const float4*)(wc1 + (hb+q)*8);
      float4 cB = *(const float4*)(wc1 + (hb+q)*8 + 4);
      ac_[0]+=gv*cA.x; ac_[1]+=gv*cA.y; ac_[2]+=gv*cA.z; ac_[3]+=gv*cA.w;
      ac_[4]+=gv*cB.x; ac_[5]+=gv*cB.y; ac_[6]+=gv*cB.z; ac_[7]+=gv*cB.w;
    }
  }
#pragma unroll
  for (int o = 0; o < 8; ++o) { ar[o] = lk(ar[o]); ac_[o] = lk(ac_[o]); }
  float jd[16];
#pragma unroll
  for (int i = 0; i < 8; ++i) jd[i] = __expf(ar[i]*DT_C) * em[i];
#pragma unroll
  for (int p = 0; p < 4; ++p) {
    float s = __expf(ac_[2*p]*DT_C);
    float th = ac_[2*p+1]*DT_C;
    float e1 = s*__cosf(th), e2 = s*__sinf(th);
    jd[8+2*p]   = (e1+e2)*em[2*p];
    jd[8+2*p+1] = (e1-e2)*em[2*p+1];
  }
  {
    float4* jp = (float4*)(jordan + (size_t)e*16);
#pragma unroll
    for (int q = 0; q < 4; ++q) {
      float4 v; v.x=jd[4*q+0]; v.y=jd[4*q+1]; v.z=jd[4*q+2]; v.w=jd[4*q+3];
      jp[q] = v;
    }
  }
  float ls = 0.f;
  if ((e & 1023) != 1023) {
    const float4* np = (const float4*)(emb + (size_t)(e+1)*16);
#pragma unroll
    for (int q = 0; q < 4; ++q) {
      float4 v = np[q];
      float d0 = v.x - jd[4*q+0], d1 = v.y - jd[4*q+1];
      float d2 = v.z - jd[4*q+2], d3 = v.w - jd[4*q+3];
      ls += d0*d0 + d1*d1 + d2*d2 + d3*d3;
    }
  }
  red[tid] = ls; __syncthreads();
  for (int s = 128; s > 0; s >>= 1) {
    if (tid < s) red[tid] += red[tid+s];
    __syncthreads();
  }
  if (tid == 0) atomicAdd(acc + 0, red[0]);
}

// ---------------- K4b: dec(jordan)+x -> out ; dec(emb) -> recon loss partials ----------------
__global__ __launch_bounds__(256) void k4b_dec(
    const float* __restrict__ emb, const float* __restrict__ jordan,
    const float* __restrict__ Wd0, const float* __restrict__ bd0,
    const uint32_t* __restrict__ Wd1P, const float* __restrict__ bd1,
    const float* __restrict__ x, float* __restrict__ out, float* __restrict__ acc)
{
  __shared__ float zl[1024];        // 64 rows x 16
  __shared__ uint32_t hl[8192];     // hidden f16 [64 r][256 h]
  __shared__ float2 red2[256];
  const int tid = threadIdx.x;
  const int y = blockIdx.y;
  const int r0 = blockIdx.x * 64;
  const float* Z = y ? jordan : emb;
  ((float4*)zl)[tid] = ((const float4*)(Z + (size_t)r0*16))[tid];
  float w0r[16];
#pragma unroll
  for (int k = 0; k < 16; ++k) w0r[k] = Wd0[k*256 + tid];
  float b0v = bd0[tid];
  __syncthreads();
  for (int r = 0; r < 64; ++r) {
    float h = b0v;
#pragma unroll
    for (int q = 0; q < 4; ++q) {
      float4 z4 = ((const float4*)zl)[r*4 + q];
      h += z4.x*w0r[4*q+0] + z4.y*w0r[4*q+1] + z4.z*w0r[4*q+2] + z4.w*w0r[4*q+3];
    }
    h = lk(h);
    ((u16*)hl)[r*256 + tid] = f2us(h);
  }
  __syncthreads();
  const int c = tid & 63, g = tid >> 6;
  float a[16];
#pragma unroll
  for (int q = 0; q < 16; ++q) a[q] = 0.f;
  for (int k4 = 0; k4 < 32; ++k4) {
    uint32_t wa = Wd1P[(4*k4+0)*64 + c];
    uint32_t wb = Wd1P[(4*k4+1)*64 + c];
    uint32_t wc = Wd1P[(4*k4+2)*64 + c];
    uint32_t wd = Wd1P[(4*k4+3)*64 + c];
#pragma unroll
    for (int rr = 0; rr < 16; ++rr) {
      uint4 h4 = *(const uint4*)(hl + (size_t)(g*16+rr)*128 + 4*k4);
      a[rr] = fdot2f(h4.x, wa, a[rr]);
      a[rr] = fdot2f(h4.y, wb, a[rr]);
      a[rr] = fdot2f(h4.z, wc, a[rr]);
      a[rr] = fdot2f(h4.w, wd, a[rr]);
    }
  }
  float bv = bd1[c];
  float ls = 0.f, xs = 0.f;
#pragma unroll
  for (int rr = 0; rr < 16; ++rr) {
    int e = r0 + g*16 + rr;
    float v = lk(a[rr] + bv);
    float xv = x[(size_t)e*64 + c];
    if (y) {
      out[(size_t)e*64 + c] = v + xv;
    } else {
      float d = v - xv;
      ls += d*d; xs += xv*xv;
    }
  }
  if (!y) {
    red2[tid] = make_float2(ls, xs);
    __syncthreads();
    for (int s = 128; s > 0; s >>= 1) {
      if (tid < s) {
        red2[tid].x += red2[tid+s].x;
        red2[tid].y += red2[tid+s].y;
      }
      __syncthreads();
    }
    if (tid == 0) { atomicAdd(acc+1, red2[0].x); atomicAdd(acc+2, red2[0].y); }
  }
}

// ---------------- K5: finalize loss ----------------
__global__ void k5_loss(const float* __restrict__ acc, float* __restrict__ out) {
  if (threadIdx.x == 0 && blockIdx.x == 0) {
    float lin = acc[0], rec = acc[1], x2 = acc[2];
    float mean = x2 * (1.0f/8388608.0f);
    float loss = rec * rcp_(mean) * (1.0f/130944.0f) + lin * (1.0f/130944.0f);
    out[8388608] = loss;
  }
}

extern "C" void kernel_launch(void* const* d_in, const int* in_sizes, int n_in,
                              void* d_out, int out_size, void* d_ws, size_t ws_size,
                              hipStream_t stream) {
  const float* x   = (const float*)d_in[0];
  const float* W1  = (const float*)d_in[1];
  const float* U1  = (const float*)d_in[2];
  const float* b1  = (const float*)d_in[3];
  const float* W2  = (const float*)d_in[4];
  const float* U2  = (const float*)d_in[5];
  const float* b2  = (const float*)d_in[6];
  const float* Ar0 = (const float*)d_in[7];
  const float* br0 = (const float*)d_in[8];
  const float* Ar1 = (const float*)d_in[9];
  const float* br1 = (const float*)d_in[10];
  const float* Ac0 = (const float*)d_in[11];
  const float* bc0 = (const float*)d_in[12];
  const float* Ac1 = (const float*)d_in[13];
  const float* bc1 = (const float*)d_in[14];
  const float* Wd0 = (const float*)d_in[15];
  const float* bd0 = (const float*)d_in[16];
  const float* Wd1 = (const float*)d_in[17];
  const float* bd1 = (const float*)d_in[18];
  char* ws = (char*)d_ws;
  uint32_t* U1P   = (uint32_t*)(ws + OFF_U1P);
  uint32_t* W1P   = (uint32_t*)(ws + OFF_W1P);
  uint32_t* W2P   = (uint32_t*)(ws + OFF_W2P);
  uint32_t* Wd1P  = (uint32_t*)(ws + OFF_WD1P);
  float* accb     = (float*)(ws + OFF_ACC);
  float* stc      = (float*)(ws + OFF_STC);
  float* sth      = (float*)(ws + OFF_STH);
  u16*   xz1c     = (u16*)(ws + OFF_BIG);
  float* xz2      = (float*)(ws + OFF_BIG);
  float* jordan   = (float*)(ws + OFF_BIG);
  u16*   emb1     = (u16*)(ws + OFF_EMB1);
  float* emb      = (float*)(ws + OFF_EMB1);
  float* outp     = (float*)d_out;

  k0_prep<<<512, 256, 0, stream>>>(W1, U1, W2, Wd1, U1P, W1P, W2P, Wd1P, accb);
  for (int ch = 0; ch < NCHUNK; ++ch) {
    k1_xz<<<dim3(256, 4), 256, 0, stream>>>(x, b1, W1P, xz1c, ch*CHUNK);
    lstm1_chunk<<<128, 512, 0, stream>>>(xz1c, U1P, emb1, stc, sth, ch*CHUNK);
  }
  k2_xz2<<<2048, 256, 0, stream>>>((const uint32_t*)emb1, W2P, b2, xz2);
  lstm2_k<<<128, 64, 0, stream>>>(xz2, U2, emb);
  k4a_jordan<<<512, 256, 0, stream>>>(emb, Ar0, br0, Ar1, br1, Ac0, bc0, Ac1, bc1, jordan, accb);
  k4b_dec<<<dim3(2048, 2), 256, 0, stream>>>(emb, jordan, Wd0, bd0, Wd1P, bd1, x, outp, accb);
  k5_loss<<<1, 64, 0, stream>>>(accb, outp);
}

// Round 2
// 7991.557 us; speedup vs baseline: 2.0640x; 2.0640x over previous
//
#include <hip/hip_runtime.h>
#include <stdint.h>

typedef unsigned short u16;

// ---------- problem constants ----------
#define BB 128
#define TT 1024
#define DD 64
#define CHUNK 128
#define NCHUNK 8
#define MTOT (BB*TT)        // 131072
#define DT_C 0.01f

// ---------- ws layout (bytes) ----------
#define OFF_U1P   0u                 // u32[128*1024]  512KB  (U1 packed half2 along K)
#define OFF_W1P   524288u            // u32[32*1024]   128KB
#define OFF_W2P   655360u            // u32[128*64]    32KB
#define OFF_WD1P  688128u            // u32[128*64]    32KB
#define OFF_U1G   720896u            // uint4[8*1024]  128KB (U1 rows 96..127, granule-major)
#define OFF_ACC   851968u            // f32[64]  [0]=lin [1]=rec [2]=x2
#define OFF_STC   852224u            // f32[128*256]   128KB (lstm1 c-state across chunks)
#define OFF_STH   983296u            // f32[128*256]   128KB (lstm1 h-state across chunks)
#define OFF_BIG   1179648u           // xz1c f16 chunk (32MB) -> xz2 f32 (32MB) -> jordan f32 (8MB)
#define OFF_EMB1  34734080u          // emb1 f16 (64MB) -> emb f32 (8MB)

typedef _Float16 h2_t __attribute__((ext_vector_type(2)));
union UH2 { uint32_t u; h2_t h; u16 s[2]; };

__device__ __forceinline__ float fdot2f(uint32_t a, uint32_t b, float c) {
#if __has_builtin(__builtin_amdgcn_fdot2)
  UH2 ua, ub; ua.u = a; ub.u = b;
  return __builtin_amdgcn_fdot2(ua.h, ub.h, c, false);
#else
  UH2 ua, ub; ua.u = a; ub.u = b;
  return c + (float)ua.h.x * (float)ub.h.x + (float)ua.h.y * (float)ub.h.y;
#endif
}

__device__ __forceinline__ uint32_t pk2(float a, float b) {
  UH2 u; u.h = h2_t{(_Float16)a, (_Float16)b}; return u.u;
}
__device__ __forceinline__ u16 f2us(float a) {
  UH2 u; u.h = h2_t{(_Float16)a, (_Float16)0.f}; return u.s[0];
}
__device__ __forceinline__ float us2f(u16 s) {
  UH2 u; u.u = (uint32_t)s; return (float)u.h.x;
}
__device__ __forceinline__ float rcp_(float x) {
#if __has_builtin(__builtin_amdgcn_rcpf)
  return __builtin_amdgcn_rcpf(x);
#else
  return 1.0f / x;
#endif
}
__device__ __forceinline__ float sigm(float x)  { return rcp_(1.0f + __expf(-x)); }
__device__ __forceinline__ float tanh_(float x) { return 1.0f - 2.0f * rcp_(__expf(2.0f*x) + 1.0f); }
__device__ __forceinline__ float lk(float v)    { return v > 0.f ? v : 0.3f*v; }

// ---------------- K0: weight prep (pack f16 pairs along K) + zero accumulators ----------------
__global__ __launch_bounds__(256) void k0_prep(
    const float* __restrict__ W1, const float* __restrict__ U1,
    const float* __restrict__ W2, const float* __restrict__ Wd1,
    uint32_t* __restrict__ U1P, uint32_t* __restrict__ W1P,
    uint32_t* __restrict__ W2P, uint32_t* __restrict__ Wd1P,
    uint4* __restrict__ U1G, float* __restrict__ acc)
{
  const int i0 = blockIdx.x*256 + threadIdx.x;
  const int st = gridDim.x*256;
  for (int i = i0; i < 131072; i += st) {
    int k2 = i >> 10, cc = i & 1023;
    U1P[i] = pk2(U1[(2*k2)*1024 + cc], U1[(2*k2+1)*1024 + cc]);
  }
  // U1G: granule-major tail rows k2=96..127: U1G[g*1024+col] = rows 96+4g..96+4g+3
  for (int i = i0; i < 8192; i += st) {
    int g = i >> 10, cc = i & 1023;
    int k2 = 96 + 4*g;
    uint4 v;
    v.x = pk2(U1[(2*(k2+0))*1024 + cc], U1[(2*(k2+0)+1)*1024 + cc]);
    v.y = pk2(U1[(2*(k2+1))*1024 + cc], U1[(2*(k2+1)+1)*1024 + cc]);
    v.z = pk2(U1[(2*(k2+2))*1024 + cc], U1[(2*(k2+2)+1)*1024 + cc]);
    v.w = pk2(U1[(2*(k2+3))*1024 + cc], U1[(2*(k2+3)+1)*1024 + cc]);
    U1G[i] = v;
  }
  for (int i = i0; i < 32768; i += st) {
    int k2 = i >> 10, cc = i & 1023;
    W1P[i] = pk2(W1[(2*k2)*1024 + cc], W1[(2*k2+1)*1024 + cc]);
  }
  for (int i = i0; i < 8192; i += st) {
    int k2 = i >> 6, cc = i & 63;
    W2P[i]  = pk2(W2[(2*k2)*64 + cc],  W2[(2*k2+1)*64 + cc]);
    Wd1P[i] = pk2(Wd1[(2*k2)*64 + cc], Wd1[(2*k2+1)*64 + cc]);
  }
  if (i0 < 64) acc[i0] = 0.f;
}

// ---------------- K1: xz1 chunk = inputs[:, t0:t0+128, :] @ W1 + b1  (f16 out) ----------------
__global__ __launch_bounds__(256) void k1_xz(
    const float* __restrict__ x, const float* __restrict__ b1,
    const uint32_t* __restrict__ W1P, u16* __restrict__ xz1c, int t0)
{
  __shared__ uint32_t wlds[8192];     // [32 k2][256 c]
  __shared__ uint32_t alds[64*33];    // [64 r][32 k2] padded
  __shared__ float blds[256];
  const int tid = threadIdx.x;
  const int c0t = blockIdx.y * 256;
  const int r0 = blockIdx.x * 64;
  for (int i = tid; i < 8192; i += 256) {
    int k2 = i >> 8, cc = i & 255;
    wlds[i] = W1P[k2*1024 + c0t + cc];
  }
  blds[tid] = b1[c0t + tid];
  if (tid < 64) {
    int rc = r0 + tid;
    int bq = rc >> 7, tc = rc & 127;
    const float4* xr = (const float4*)(x + ((size_t)bq*TT + t0 + tc) * 64);
#pragma unroll
    for (int q = 0; q < 16; ++q) {
      float4 v = xr[q];
      alds[tid*33 + 2*q]   = pk2(v.x, v.y);
      alds[tid*33 + 2*q+1] = pk2(v.z, v.w);
    }
  }
  __syncthreads();
  const int r = tid & 63, grp = tid >> 6;
  float acc[64];
#pragma unroll
  for (int q = 0; q < 64; ++q) acc[q] = 0.f;
  const uint4* w4p = (const uint4*)wlds;
  for (int k2 = 0; k2 < 32; ++k2) {
    uint32_t a2 = alds[r*33 + k2];
#pragma unroll
    for (int jj = 0; jj < 16; ++jj) {
      uint4 w = w4p[k2*64 + grp*16 + jj];
      acc[4*jj+0] = fdot2f(a2, w.x, acc[4*jj+0]);
      acc[4*jj+1] = fdot2f(a2, w.y, acc[4*jj+1]);
      acc[4*jj+2] = fdot2f(a2, w.z, acc[4*jj+2]);
      acc[4*jj+3] = fdot2f(a2, w.w, acc[4*jj+3]);
    }
  }
  int rc = r0 + r;
  uint32_t* dst = (uint32_t*)(xz1c + (size_t)rc*1024 + c0t + grp*64);
  const float4* bl4 = (const float4*)blds;
#pragma unroll
  for (int jj = 0; jj < 16; ++jj) {
    float4 bv = bl4[grp*16 + jj];
    dst[2*jj]   = pk2(acc[4*jj+0] + bv.x, acc[4*jj+1] + bv.y);
    dst[2*jj+1] = pk2(acc[4*jj+2] + bv.z, acc[4*jj+3] + bv.w);
  }
}

// ---------------- LSTM1 v2: 256 thr/block, thread j owns unit j (4 gate cols) ----------------
// Weights split: k2 0..83 regs (336 VGPR), 84..95 LDS (swizzled), 96..127 global L2 stream.
#define RDOT(R) { uint4 h4 = h4p[R]; \
  uint4 wa = wv[4*(R)+0], wb = wv[4*(R)+1], wc = wv[4*(R)+2], wd = wv[4*(R)+3]; \
  z0 = fdot2f(wa.x, h4.x, z0); y0 = fdot2f(wb.x, h4.y, y0); \
  z0 = fdot2f(wc.x, h4.z, z0); y0 = fdot2f(wd.x, h4.w, y0); \
  z1 = fdot2f(wa.y, h4.x, z1); y1 = fdot2f(wb.y, h4.y, y1); \
  z1 = fdot2f(wc.y, h4.z, z1); y1 = fdot2f(wd.y, h4.w, y1); \
  z2 = fdot2f(wa.z, h4.x, z2); y2 = fdot2f(wb.z, h4.y, y2); \
  z2 = fdot2f(wc.z, h4.z, z2); y2 = fdot2f(wd.z, h4.w, y2); \
  z3 = fdot2f(wa.w, h4.x, z3); y3 = fdot2f(wb.w, h4.y, y3); \
  z3 = fdot2f(wc.w, h4.z, z3); y3 = fdot2f(wd.w, h4.w, y3); }

#define GLOAD(G) \
  uint4 ga##G = U1G[(G)*1024 + j       + gof]; \
  uint4 gb##G = U1G[(G)*1024 + j + 256 + gof]; \
  uint4 gc##G = U1G[(G)*1024 + j + 512 + gof]; \
  uint4 gd##G = U1G[(G)*1024 + j + 768 + gof];

#define GCONS(G) { uint4 h4 = h4p[24+(G)]; \
  z0 = fdot2f(ga##G.x, h4.x, z0); y0 = fdot2f(ga##G.y, h4.y, y0); \
  z0 = fdot2f(ga##G.z, h4.z, z0); y0 = fdot2f(ga##G.w, h4.w, y0); \
  z1 = fdot2f(gb##G.x, h4.x, z1); y1 = fdot2f(gb##G.y, h4.y, y1); \
  z1 = fdot2f(gb##G.z, h4.z, z1); y1 = fdot2f(gb##G.w, h4.w, y1); \
  z2 = fdot2f(gc##G.x, h4.x, z2); y2 = fdot2f(gc##G.y, h4.y, y2); \
  z2 = fdot2f(gc##G.z, h4.z, z2); y2 = fdot2f(gc##G.w, h4.w, y2); \
  z3 = fdot2f(gd##G.x, h4.x, z3); y3 = fdot2f(gd##G.y, h4.y, y3); \
  z3 = fdot2f(gd##G.z, h4.z, z3); y3 = fdot2f(gd##G.w, h4.w, y3); }

#define LCONS(G) { uint4 h4 = h4p[21+(G)]; int sl = (((G)^m)*4) + lof; \
  uint4 u0 = *(const uint4*)&ulds[(j      )*16 + sl]; \
  uint4 u1 = *(const uint4*)&ulds[(j+256)*16 + sl]; \
  uint4 u2 = *(const uint4*)&ulds[(j+512)*16 + sl]; \
  uint4 u3 = *(const uint4*)&ulds[(j+768)*16 + sl]; \
  z0 = fdot2f(u0.x, h4.x, z0); y0 = fdot2f(u0.y, h4.y, y0); \
  z0 = fdot2f(u0.z, h4.z, z0); y0 = fdot2f(u0.w, h4.w, y0); \
  z1 = fdot2f(u1.x, h4.x, z1); y1 = fdot2f(u1.y, h4.y, y1); \
  z1 = fdot2f(u1.z, h4.z, z1); y1 = fdot2f(u1.w, h4.w, y1); \
  z2 = fdot2f(u2.x, h4.x, z2); y2 = fdot2f(u2.y, h4.y, y2); \
  z2 = fdot2f(u2.z, h4.z, z2); y2 = fdot2f(u2.w, h4.w, y2); \
  z3 = fdot2f(u3.x, h4.x, z3); y3 = fdot2f(u3.y, h4.y, y3); \
  z3 = fdot2f(u3.z, h4.z, z3); y3 = fdot2f(u3.w, h4.w, y3); }

__global__ __launch_bounds__(256, 1) void lstm1_chunk(
    const u16* __restrict__ xz1c, const uint32_t* __restrict__ U1P,
    const uint4* __restrict__ U1G, u16* __restrict__ emb1,
    float* __restrict__ stc, float* __restrict__ sth, int t0)
{
  __shared__ uint32_t ulds[1024*16];   // 64KB: [col][4 uint4 slots] XOR-swizzled (3 used)
  __shared__ uint32_t hsh[2][128];     // double-buffered h (packed half2)

  const int j = threadIdx.x;
  const int b = blockIdx.x;
  const int m = j & 3;

  // register weights: k2 rows 0..83, all 4 gate columns of unit j
  uint4 wv[84];
#pragma unroll
  for (int r = 0; r < 84; ++r) {
    wv[r].x = U1P[r*1024 + j];
    wv[r].y = U1P[r*1024 + j + 256];
    wv[r].z = U1P[r*1024 + j + 512];
    wv[r].w = U1P[r*1024 + j + 768];
  }
  // LDS weights: k2 rows 84..95 (3 granules of 4), swizzled slot = (g ^ (col&3))
#pragma unroll
  for (int c = 0; c < 4; ++c) {
    int col = j + 256*c;
#pragma unroll
    for (int g = 0; g < 3; ++g) {
      uint4 v;
      v.x = U1P[(84+4*g+0)*1024 + col];
      v.y = U1P[(84+4*g+1)*1024 + col];
      v.z = U1P[(84+4*g+2)*1024 + col];
      v.w = U1P[(84+4*g+3)*1024 + col];
      *(uint4*)&ulds[col*16 + ((g ^ m)*4)] = v;
    }
  }
  float cst = 0.f, hlast = 0.f;
  {
    float hv = 0.f;
    if (t0 != 0) { cst = stc[b*256 + j]; hv = sth[b*256 + j]; }
    hlast = hv;
    ((u16*)hsh[0])[j] = f2us(hv);
  }
  __syncthreads();

  const u16* xzb = xz1c + (size_t)b * CHUNK * 1024;
  u16 xv0 = xzb[j], xv1 = xzb[j+256], xv2 = xzb[j+512], xv3 = xzb[j+768];
  u16* embp = emb1 + ((size_t)b*TT + t0)*256 + j;
  int cur = 0;

  for (int t = 0; t < CHUNK; ++t) {
    int lof = 0; asm volatile("" : "+v"(lof));   // block loop-invariant hoist of LDS tail
    int gof = 0; asm volatile("" : "+v"(gof));   // block loop-invariant hoist of global tail

    u16 nx0 = 0, nx1 = 0, nx2 = 0, nx3 = 0;
    if (t + 1 < CHUNK) {
      const u16* nxt = xzb + (size_t)(t+1)*1024;
      nx0 = nxt[j]; nx1 = nxt[j+256]; nx2 = nxt[j+512]; nx3 = nxt[j+768];
    }
    const uint4* h4p = (const uint4*)hsh[cur];
    float z0 = us2f(xv0), z1 = us2f(xv1), z2 = us2f(xv2), z3 = us2f(xv3);
    float y0 = 0.f, y1 = 0.f, y2 = 0.f, y3 = 0.f;

    // 3-deep pipelined global tail interleaved with register dot-product
    GLOAD(0) GLOAD(1) GLOAD(2)
    RDOT(0)  RDOT(1)  RDOT(2)
    GCONS(0) GLOAD(3)
    RDOT(3)  RDOT(4)  RDOT(5)
    GCONS(1) GLOAD(4)
    RDOT(6)  RDOT(7)  RDOT(8)
    GCONS(2) GLOAD(5)
    RDOT(9)  RDOT(10) RDOT(11)
    GCONS(3) GLOAD(6)
    RDOT(12) RDOT(13) RDOT(14)
    GCONS(4) GLOAD(7)
    RDOT(15) RDOT(16)
    GCONS(5)
    RDOT(17) RDOT(18)
    GCONS(6)
    RDOT(19) RDOT(20)
    GCONS(7)
    LCONS(0) LCONS(1) LCONS(2)

    float zi = z0 + y0, zf = z1 + y1, zg = z2 + y2, zo = z3 + y3;
    float iv = sigm(zi), fv = sigm(zf), gv = tanh_(zg), ov = sigm(zo);
    cst = fv * cst + iv * gv;
    float hval = ov * tanh_(cst);
    hlast = hval;
    u16 hu = f2us(hval);
    ((u16*)hsh[cur ^ 1])[j] = hu;
    embp[(size_t)t*256] = hu;
    __syncthreads();
    cur ^= 1;
    xv0 = nx0; xv1 = nx1; xv2 = nx2; xv3 = nx3;
  }
  stc[b*256 + j] = cst;
  sth[b*256 + j] = hlast;
}

// ---------------- K2: xz2 = emb1 @ W2 + b2  (f32 out) ----------------
__global__ __launch_bounds__(256) void k2_xz2(
    const uint32_t* __restrict__ emb1u, const uint32_t* __restrict__ W2P,
    const float* __restrict__ b2, float* __restrict__ xz2)
{
  __shared__ uint32_t alds[64*129];   // [64 r][128 k2] padded
  const int tid = threadIdx.x;
  const int r0 = blockIdx.x * 64;
  for (int i = tid; i < 8192; i += 256) {
    int row = i >> 7, k2 = i & 127;
    alds[row*129 + k2] = emb1u[(size_t)(r0 + row)*128 + k2];
  }
  __syncthreads();
  const int r = tid & 63, grp = tid >> 6;
  float acc[16];
#pragma unroll
  for (int q = 0; q < 16; ++q) acc[q] = 0.f;
  for (int k2 = 0; k2 < 128; ++k2) {
    uint32_t a2 = alds[r*129 + k2];
    const uint4* wp = (const uint4*)(W2P + k2*64 + grp*16);
#pragma unroll
    for (int q = 0; q < 4; ++q) {
      uint4 w = wp[q];
      acc[4*q+0] = fdot2f(a2, w.x, acc[4*q+0]);
      acc[4*q+1] = fdot2f(a2, w.y, acc[4*q+1]);
      acc[4*q+2] = fdot2f(a2, w.z, acc[4*q+2]);
      acc[4*q+3] = fdot2f(a2, w.w, acc[4*q+3]);
    }
  }
  float* dst = xz2 + (size_t)(r0 + r)*64 + grp*16;
#pragma unroll
  for (int q = 0; q < 4; ++q) {
    float4 bv = *(const float4*)(b2 + grp*16 + 4*q);
    float4 o;
    o.x = acc[4*q+0]+bv.x; o.y = acc[4*q+1]+bv.y;
    o.z = acc[4*q+2]+bv.z; o.w = acc[4*q+3]+bv.w;
    *(float4*)(dst + 4*q) = o;
  }
}

// ---------------- LSTM2: per-batch, 16 hidden units ----------------
__global__ __launch_bounds__(64) void lstm2_k(
    const float* __restrict__ xz2, const float* __restrict__ U2,
    float* __restrict__ emb)
{
  __shared__ float hsh[16];
  __shared__ float zsh[64];
  const int j = threadIdx.x;
  const int b = blockIdx.x;
  float u2[16];
#pragma unroll
  for (int k = 0; k < 16; ++k) u2[k] = U2[k*64 + j];
  if (j < 16) hsh[j] = 0.f;
  float cst = 0.f;
  __syncthreads();
  const float* xb = xz2 + (size_t)b * TT * 64;
  float xv = xb[j];
  for (int t = 0; t < TT; ++t) {
    float nx = 0.f;
    if (t + 1 < TT) nx = xb[(size_t)(t+1)*64 + j];
    float z = xv;
#pragma unroll
    for (int k = 0; k < 16; ++k) z += hsh[k] * u2[k];
    float av = (j >= 32 && j < 48) ? tanh_(z) : sigm(z);
    zsh[j] = av;
    __syncthreads();
    if (j < 16) {
      float iv = zsh[j], fv = zsh[j+16], gv = zsh[j+32], ov = zsh[j+48];
      cst = fv * cst + iv * gv;
      float hval = ov * tanh_(cst);
      hsh[j] = hval;
      emb[((size_t)b*TT + t)*16 + j] = hval;
    }
    __syncthreads();
    xv = nx;
  }
}

// ---------------- K4a: oreal/ocplx MLPs -> jordan, lin-loss partial ----------------
__global__ __launch_bounds__(256) void k4a_jordan(
    const float* __restrict__ emb,
    const float* __restrict__ Ar0, const float* __restrict__ br0,
    const float* __restrict__ Ar1, const float* __restrict__ br1,
    const float* __restrict__ Ac0, const float* __restrict__ bc0,
    const float* __restrict__ Ac1, const float* __restrict__ bc1,
    float* __restrict__ jordan, float* __restrict__ acc)
{
  __shared__ float wr0[1024], wr1[1024], wc0[1024], wc1[1024];
  __shared__ float bs0[128], bs2[128];
  __shared__ float bs1[8], bs3[8];
  __shared__ float red[256];
  const int tid = threadIdx.x;
  for (int i = tid; i < 1024; i += 256) {
    wr0[i] = Ar0[i]; wr1[i] = Ar1[i]; wc0[i] = Ac0[i]; wc1[i] = Ac1[i];
  }
  if (tid < 128) { bs0[tid] = br0[tid]; bs2[tid] = bc0[tid]; }
  if (tid < 8)   { bs1[tid] = br1[tid]; bs3[tid] = bc1[tid]; }
  __syncthreads();
  const int e = blockIdx.x * 256 + tid;
  float em[16];
  {
    const float4* ep = (const float4*)(emb + (size_t)e*16);
#pragma unroll
    for (int q = 0; q < 4; ++q) {
      float4 v = ep[q];
      em[4*q+0]=v.x; em[4*q+1]=v.y; em[4*q+2]=v.z; em[4*q+3]=v.w;
    }
  }
  float ar[8], ac_[8];
#pragma unroll
  for (int o = 0; o < 8; ++o) { ar[o] = bs1[o]; ac_[o] = bs3[o]; }
  for (int hb = 0; hb < 128; hb += 4) {
    float4 hr = *(const float4*)(bs0 + hb);
    float4 hc = *(const float4*)(bs2 + hb);
#pragma unroll
    for (int k = 0; k < 8; ++k) {
      float4 w = *(const float4*)(wr0 + k*128 + hb);
      hr.x += em[k]*w.x; hr.y += em[k]*w.y; hr.z += em[k]*w.z; hr.w += em[k]*w.w;
      float4 v = *(const float4*)(wc0 + k*128 + hb);
      hc.x += em[8+k]*v.x; hc.y += em[8+k]*v.y; hc.z += em[8+k]*v.z; hc.w += em[8+k]*v.w;
    }
    hr.x = lk(hr.x); hr.y = lk(hr.y); hr.z = lk(hr.z); hr.w = lk(hr.w);
    hc.x = lk(hc.x); hc.y = lk(hc.y); hc.z = lk(hc.z); hc.w = lk(hc.w);
#pragma unroll
    for (int q = 0; q < 4; ++q) {
      float hv = (q==0) ? hr.x : (q==1) ? hr.y : (q==2) ? hr.z : hr.w;
      float gv = (q==0) ? hc.x : (q==1) ? hc.y : (q==2) ? hc.z : hc.w;
      float4 wA = *(const float4*)(wr1 + (hb+q)*8);
      float4 wB = *(const float4*)(wr1 + (hb+q)*8 + 4);
      ar[0]+=hv*wA.x; ar[1]+=hv*wA.y; ar[2]+=hv*wA.z; ar[3]+=hv*wA.w;
      ar[4]+=hv*wB.x; ar[5]+=hv*wB.y; ar[6]+=hv*wB.z; ar[7]+=hv*wB.w;
      float4 cA = *(const float4*)(wc1 + (hb+q)*8);
      float4 cB = *(const float4*)(wc1 + (hb+q)*8 + 4);
      ac_[0]+=gv*cA.x; ac_[1]+=gv*cA.y; ac_[2]+=gv*cA.z; ac_[3]+=gv*cA.w;
      ac_[4]+=gv*cB.x; ac_[5]+=gv*cB.y; ac_[6]+=gv*cB.z; ac_[7]+=gv*cB.w;
    }
  }
#pragma unroll
  for (int o = 0; o < 8; ++o) { ar[o] = lk(ar[o]); ac_[o] = lk(ac_[o]); }
  float jd[16];
#pragma unroll
  for (int i = 0; i < 8; ++i) jd[i] = __expf(ar[i]*DT_C) * em[i];
#pragma unroll
  for (int p = 0; p < 4; ++p) {
    float s = __expf(ac_[2*p]*DT_C);
    float th = ac_[2*p+1]*DT_C;
    float e1 = s*__cosf(th), e2 = s*__sinf(th);
    jd[8+2*p]   = (e1+e2)*em[2*p];
    jd[8+2*p+1] = (e1-e2)*em[2*p+1];
  }
  {
    float4* jp = (float4*)(jordan + (size_t)e*16);
#pragma unroll
    for (int q = 0; q < 4; ++q) {
      float4 v; v.x=jd[4*q+0]; v.y=jd[4*q+1]; v.z=jd[4*q+2]; v.w=jd[4*q+3];
      jp[q] = v;
    }
  }
  float ls = 0.f;
  if ((e & 1023) != 1023) {
    const float4* np = (const float4*)(emb + (size_t)(e+1)*16);
#pragma unroll
    for (int q = 0; q < 4; ++q) {
      float4 v = np[q];
      float d0 = v.x - jd[4*q+0], d1 = v.y - jd[4*q+1];
      float d2 = v.z - jd[4*q+2], d3 = v.w - jd[4*q+3];
      ls += d0*d0 + d1*d1 + d2*d2 + d3*d3;
    }
  }
  red[tid] = ls; __syncthreads();
  for (int s = 128; s > 0; s >>= 1) {
    if (tid < s) red[tid] += red[tid+s];
    __syncthreads();
  }
  if (tid == 0) atomicAdd(acc + 0, red[0]);
}

// ---------------- K4b: dec(jordan)+x -> out ; dec(emb) -> recon loss partials ----------------
__global__ __launch_bounds__(256) void k4b_dec(
    const float* __restrict__ emb, const float* __restrict__ jordan,
    const float* __restrict__ Wd0, const float* __restrict__ bd0,
    const uint32_t* __restrict__ Wd1P, const float* __restrict__ bd1,
    const float* __restrict__ x, float* __restrict__ out, float* __restrict__ acc)
{
  __shared__ float zl[1024];        // 64 rows x 16
  __shared__ uint32_t hl[8192];     // hidden f16 [64 r][256 h]
  __shared__ float2 red2[256];
  const int tid = threadIdx.x;
  const int y = blockIdx.y;
  const int r0 = blockIdx.x * 64;
  const float* Z = y ? jordan : emb;
  ((float4*)zl)[tid] = ((const float4*)(Z + (size_t)r0*16))[tid];
  float w0r[16];
#pragma unroll
  for (int k = 0; k < 16; ++k) w0r[k] = Wd0[k*256 + tid];
  float b0v = bd0[tid];
  __syncthreads();
  for (int r = 0; r < 64; ++r) {
    float h = b0v;
#pragma unroll
    for (int q = 0; q < 4; ++q) {
      float4 z4 = ((const float4*)zl)[r*4 + q];
      h += z4.x*w0r[4*q+0] + z4.y*w0r[4*q+1] + z4.z*w0r[4*q+2] + z4.w*w0r[4*q+3];
    }
    h = lk(h);
    ((u16*)hl)[r*256 + tid] = f2us(h);
  }
  __syncthreads();
  const int c = tid & 63, g = tid >> 6;
  float a[16];
#pragma unroll
  for (int q = 0; q < 16; ++q) a[q] = 0.f;
  for (int k4 = 0; k4 < 32; ++k4) {
    uint32_t wa = Wd1P[(4*k4+0)*64 + c];
    uint32_t wb = Wd1P[(4*k4+1)*64 + c];
    uint32_t wc = Wd1P[(4*k4+2)*64 + c];
    uint32_t wd = Wd1P[(4*k4+3)*64 + c];
#pragma unroll
    for (int rr = 0; rr < 16; ++rr) {
      uint4 h4 = *(const uint4*)(hl + (size_t)(g*16+rr)*128 + 4*k4);
      a[rr] = fdot2f(h4.x, wa, a[rr]);
      a[rr] = fdot2f(h4.y, wb, a[rr]);
      a[rr] = fdot2f(h4.z, wc, a[rr]);
      a[rr] = fdot2f(h4.w, wd, a[rr]);
    }
  }
  float bv = bd1[c];
  float ls = 0.f, xs = 0.f;
#pragma unroll
  for (int rr = 0; rr < 16; ++rr) {
    int e = r0 + g*16 + rr;
    float v = lk(a[rr] + bv);
    float xv = x[(size_t)e*64 + c];
    if (y) {
      out[(size_t)e*64 + c] = v + xv;
    } else {
      float d = v - xv;
      ls += d*d; xs += xv*xv;
    }
  }
  if (!y) {
    red2[tid] = make_float2(ls, xs);
    __syncthreads();
    for (int s = 128; s > 0; s >>= 1) {
      if (tid < s) {
        red2[tid].x += red2[tid+s].x;
        red2[tid].y += red2[tid+s].y;
      }
      __syncthreads();
    }
    if (tid == 0) { atomicAdd(acc+1, red2[0].x); atomicAdd(acc+2, red2[0].y); }
  }
}

// ---------------- K5: finalize loss ----------------
__global__ void k5_loss(const float* __restrict__ acc, float* __restrict__ out) {
  if (threadIdx.x == 0 && blockIdx.x == 0) {
    float lin = acc[0], rec = acc[1], x2 = acc[2];
    float mean = x2 * (1.0f/8388608.0f);
    float loss = rec * rcp_(mean) * (1.0f/130944.0f) + lin * (1.0f/130944.0f);
    out[8388608] = loss;
  }
}

extern "C" void kernel_launch(void* const* d_in, const int* in_sizes, int n_in,
                              void* d_out, int out_size, void* d_ws, size_t ws_size,
                              hipStream_t stream) {
  const float* x   = (const float*)d_in[0];
  const float* W1  = (const float*)d_in[1];
  const float* U1  = (const float*)d_in[2];
  const float* b1  = (const float*)d_in[3];
  const float* W2  = (const float*)d_in[4];
  const float* U2  = (const float*)d_in[5];
  const float* b2  = (const float*)d_in[6];
  const float* Ar0 = (const float*)d_in[7];
  const float* br0 = (const float*)d_in[8];
  const float* Ar1 = (const float*)d_in[9];
  const float* br1 = (const float*)d_in[10];
  const float* Ac0 = (const float*)d_in[11];
  const float* bc0 = (const float*)d_in[12];
  const float* Ac1 = (const float*)d_in[13];
  const float* bc1 = (const float*)d_in[14];
  const float* Wd0 = (const float*)d_in[15];
  const float* bd0 = (const float*)d_in[16];
  const float* Wd1 = (const float*)d_in[17];
  const float* bd1 = (const float*)d_in[18];
  char* ws = (char*)d_ws;
  uint32_t* U1P   = (uint32_t*)(ws + OFF_U1P);
  uint32_t* W1P   = (uint32_t*)(ws + OFF_W1P);
  uint32_t* W2P   = (uint32_t*)(ws + OFF_W2P);
  uint32_t* Wd1P  = (uint32_t*)(ws + OFF_WD1P);
  uint4*    U1G   = (uint4*)(ws + OFF_U1G);
  float* accb     = (float*)(ws + OFF_ACC);
  float* stc      = (float*)(ws + OFF_STC);
  float* sth      = (float*)(ws + OFF_STH);
  u16*   xz1c     = (u16*)(ws + OFF_BIG);
  float* xz2      = (float*)(ws + OFF_BIG);
  float* jordan   = (float*)(ws + OFF_BIG);
  u16*   emb1     = (u16*)(ws + OFF_EMB1);
  float* emb      = (float*)(ws + OFF_EMB1);
  float* outp     = (float*)d_out;

  k0_prep<<<512, 256, 0, stream>>>(W1, U1, W2, Wd1, U1P, W1P, W2P, Wd1P, U1G, accb);
  for (int ch = 0; ch < NCHUNK; ++ch) {
    k1_xz<<<dim3(256, 4), 256, 0, stream>>>(x, b1, W1P, xz1c, ch*CHUNK);
    lstm1_chunk<<<128, 256, 0, stream>>>(xz1c, U1P, U1G, emb1, stc, sth, ch*CHUNK);
  }
  k2_xz2<<<2048, 256, 0, stream>>>((const uint32_t*)emb1, W2P, b2, xz2);
  lstm2_k<<<128, 64, 0, stream>>>(xz2, U2, emb);
  k4a_jordan<<<512, 256, 0, stream>>>(emb, Ar0, br0, Ar1, br1, Ac0, bc0, Ac1, bc1, jordan, accb);
  k4b_dec<<<dim3(2048, 2), 256, 0, stream>>>(emb, jordan, Wd0, bd0, Wd1P, bd1, x, outp, accb);
  k5_loss<<<1, 64, 0, stream>>>(accb, outp);
}